// Round 3
// baseline (958.935 us; speedup 1.0000x reference)
//
#include <hip/hip_runtime.h>

#define S_LEN 2048
#define D_MODEL 1024
#define N3 3072
#define NHEAD 16
#define DHEAD 64

// ---------------- GEMM1: kqv = inputs @ W + b ----------------
// A: [M=4096, K=1024] row-major; W: [1024, 3072] row-major; C: [4096, 3072]
// 64x64 tile, BK=32, 4x4 micro-tile per thread (256 threads).
__global__ __launch_bounds__(256) void gemm_kqv(
        const float* __restrict__ A, const float* __restrict__ Wm,
        const float* __restrict__ bias, float* __restrict__ C) {
    __shared__ float Ast[32][68];   // [k][m]  (transposed so A-frag is contiguous)
    __shared__ float Bs[32][68];    // [k][n]
    const int tid = threadIdx.x;
    const int n0 = blockIdx.x * 64;
    const int m0 = blockIdx.y * 64;
    const int tm = tid >> 4;        // 0..15
    const int tn = tid & 15;        // 0..15
    const int am = tid >> 2;        // 0..63  (A staging row)
    const int ak = (tid & 3) * 8;   // 0,8,16,24
    const int bk = tid >> 3;        // 0..31  (B staging row)
    const int bn = (tid & 7) * 8;   // 0,8,...,56
    float acc[4][4] = {};
    for (int k0 = 0; k0 < D_MODEL; k0 += 32) {
        float4 a0 = *(const float4*)&A[(size_t)(m0 + am) * D_MODEL + k0 + ak];
        float4 a1 = *(const float4*)&A[(size_t)(m0 + am) * D_MODEL + k0 + ak + 4];
        float4 b0 = *(const float4*)&Wm[(size_t)(k0 + bk) * N3 + n0 + bn];
        float4 b1 = *(const float4*)&Wm[(size_t)(k0 + bk) * N3 + n0 + bn + 4];
        __syncthreads();            // previous iteration's reads complete
        Ast[ak+0][am]=a0.x; Ast[ak+1][am]=a0.y; Ast[ak+2][am]=a0.z; Ast[ak+3][am]=a0.w;
        Ast[ak+4][am]=a1.x; Ast[ak+5][am]=a1.y; Ast[ak+6][am]=a1.z; Ast[ak+7][am]=a1.w;
        *(float4*)&Bs[bk][bn]   = b0;
        *(float4*)&Bs[bk][bn+4] = b1;
        __syncthreads();
        #pragma unroll
        for (int kk = 0; kk < 32; ++kk) {
            float4 av = *(const float4*)&Ast[kk][tm*4];
            float4 bv = *(const float4*)&Bs[kk][tn*4];
            float a[4] = {av.x, av.y, av.z, av.w};
            float b[4] = {bv.x, bv.y, bv.z, bv.w};
            #pragma unroll
            for (int i = 0; i < 4; ++i)
                #pragma unroll
                for (int j = 0; j < 4; ++j)
                    acc[i][j] = fmaf(a[i], b[j], acc[i][j]);
        }
    }
    const int col = n0 + tn * 4;
    float4 bb = *(const float4*)&bias[col];
    #pragma unroll
    for (int i = 0; i < 4; ++i) {
        int row = m0 + tm * 4 + i;
        float4 o = make_float4(acc[i][0]+bb.x, acc[i][1]+bb.y,
                               acc[i][2]+bb.z, acc[i][3]+bb.w);
        *(float4*)&C[(size_t)row * N3 + col] = o;
    }
}

// ---------------- Fused attention ----------------
// Per block: one (batch, head, 64-query block). Flash-style single pass over
// 64-key tiles. Weights are bounded by e^10 (elu-clip), so no online max is
// needed: accumulate numerator & denominator directly in fp32.
__global__ __launch_bounds__(256) void attn_fused(
        const float* __restrict__ kqv, const float* __restrict__ masks,
        float* __restrict__ out) {
    __shared__ float Qt[64][68];   // [dd][q]  transposed
    __shared__ float Kt[64][68];   // [dd][k]  transposed
    __shared__ float Vs[64][68];   // [k][dd]  row-major
    __shared__ float Wt[64][68];   // [k][q]   weights transposed
    __shared__ float maskS[64];
    const int tid = threadIdx.x;
    const int qb = blockIdx.x;     // 0..31
    const int h  = blockIdx.y;     // 0..15
    const int b  = blockIdx.z;     // 0..1
    const int q0 = qb * 64;
    const int tq = tid >> 4;       // 0..15  (query group)
    const int tc = tid & 15;       // 0..15  (key group in QK, dd group in PV)
    const int sr = tid >> 2;       // 0..63  staging row
    const int sc = (tid & 3) * 16; // staging col base

    const size_t rowbase = (size_t)(b * S_LEN) * N3;

    // stage Q transposed (once per block)
    {
        const float* qp = kqv + rowbase + (size_t)(q0 + sr) * N3 + D_MODEL + h * DHEAD;
        #pragma unroll
        for (int t = 0; t < 4; ++t) {
            int c = sc + t * 4;
            float4 v = *(const float4*)&qp[c];
            Qt[c+0][sr]=v.x; Qt[c+1][sr]=v.y; Qt[c+2][sr]=v.z; Qt[c+3][sr]=v.w;
        }
    }

    float num[4][4] = {};
    float den[4] = {};

    for (int k0 = 0; k0 < S_LEN; k0 += 64) {
        __syncthreads();   // previous tile's PV reads complete (also orders Q stage)
        const float* kp = kqv + rowbase + (size_t)(k0 + sr) * N3 + h * DHEAD;
        const float* vp = kqv + rowbase + (size_t)(k0 + sr) * N3 + 2 * D_MODEL + h * DHEAD;
        #pragma unroll
        for (int t = 0; t < 4; ++t) {
            int c = sc + t * 4;
            float4 kv = *(const float4*)&kp[c];
            Kt[c+0][sr]=kv.x; Kt[c+1][sr]=kv.y; Kt[c+2][sr]=kv.z; Kt[c+3][sr]=kv.w;
            float4 vv = *(const float4*)&vp[c];
            *(float4*)&Vs[sr][c] = vv;
        }
        if (tid < 64) maskS[tid] = masks[b * S_LEN + k0 + tid];
        __syncthreads();

        // U = Q·K^T : u[i][j] for q = q0+tq*4+i, k = k0+tc*4+j
        float u[4][4] = {};
        #pragma unroll 16
        for (int dd = 0; dd < 64; ++dd) {
            float4 av = *(const float4*)&Qt[dd][tq*4];
            float4 bv = *(const float4*)&Kt[dd][tc*4];
            float a[4]  = {av.x, av.y, av.z, av.w};
            float bb[4] = {bv.x, bv.y, bv.z, bv.w};
            #pragma unroll
            for (int i = 0; i < 4; ++i)
                #pragma unroll
                for (int j = 0; j < 4; ++j)
                    u[i][j] = fmaf(a[i], bb[j], u[i][j]);
        }
        // w = exp(clip(elu(u))) * mask_k ; accumulate denominator
        float w[4][4];
        #pragma unroll
        for (int i = 0; i < 4; ++i) {
            #pragma unroll
            for (int j = 0; j < 4; ++j) {
                float x = u[i][j];
                float t = x > 0.0f ? x : (__expf(x) - 1.0f);  // elu (lower clip moot: elu > -1)
                t = fminf(t, 10.0f);
                float e = __expf(t) * maskS[tc*4 + j];
                w[i][j] = e;
                den[i] += e;
            }
        }
        #pragma unroll
        for (int j = 0; j < 4; ++j)
            *(float4*)&Wt[tc*4+j][tq*4] = make_float4(w[0][j], w[1][j], w[2][j], w[3][j]);
        __syncthreads();

        // PV: num[i][j] += Wt[k][q] * Vs[k][dd]
        #pragma unroll 16
        for (int k = 0; k < 64; ++k) {
            float4 av = *(const float4*)&Wt[k][tq*4];
            float4 bv = *(const float4*)&Vs[k][tc*4];
            float a[4]  = {av.x, av.y, av.z, av.w};
            float bb[4] = {bv.x, bv.y, bv.z, bv.w};
            #pragma unroll
            for (int i = 0; i < 4; ++i)
                #pragma unroll
                for (int j = 0; j < 4; ++j)
                    num[i][j] = fmaf(a[i], bb[j], num[i][j]);
        }
    }

    // reduce denominator across the 16 lanes sharing tq (consecutive lanes)
    #pragma unroll
    for (int i = 0; i < 4; ++i) {
        float d = den[i];
        d += __shfl_xor(d, 1);
        d += __shfl_xor(d, 2);
        d += __shfl_xor(d, 4);
        d += __shfl_xor(d, 8);
        den[i] = d;
    }
    // output: num/den * mask_q
    #pragma unroll
    for (int i = 0; i < 4; ++i) {
        int q = q0 + tq*4 + i;
        float mq = masks[b * S_LEN + q];
        float scale = mq / den[i];
        float4 o = make_float4(num[i][0]*scale, num[i][1]*scale,
                               num[i][2]*scale, num[i][3]*scale);
        *(float4*)&out[(size_t)(b * S_LEN + q) * D_MODEL + h * DHEAD + tc*4] = o;
    }
}

extern "C" void kernel_launch(void* const* d_in, const int* in_sizes, int n_in,
                              void* d_out, int out_size, void* d_ws, size_t ws_size,
                              hipStream_t stream) {
    (void)in_sizes; (void)n_in; (void)out_size; (void)ws_size;
    const float* inputs = (const float*)d_in[0];
    const float* masks  = (const float*)d_in[1];
    const float* Wm     = (const float*)d_in[2];
    const float* bias   = (const float*)d_in[3];
    float* outp = (float*)d_out;
    float* kqv  = (float*)d_ws;   // needs 4096*3072*4 = 50,331,648 bytes of d_ws

    // kqv = inputs @ W + b   (M=4096, N=3072, K=1024)
    gemm_kqv<<<dim3(N3/64, (2*S_LEN)/64), 256, 0, stream>>>(inputs, Wm, bias, kqv);
    // fused elu-clip-exp attention
    attn_fused<<<dim3(S_LEN/64, NHEAD, 2), 256, 0, stream>>>(kqv, masks, outp);
}

// Round 4
// 457.248 us; speedup vs baseline: 2.0972x; 2.0972x over previous
//
#include <hip/hip_runtime.h>

#define S_LEN 2048
#define D_MODEL 1024
#define NHEAD 16
#define DHEAD 64

typedef __attribute__((ext_vector_type(8))) short bf16x8;
typedef __attribute__((ext_vector_type(4))) float f32x4;

__device__ __forceinline__ unsigned short bf16_rne(float x) {
    unsigned int u = __float_as_uint(x);
    u += 0x7FFFu + ((u >> 16) & 1u);
    return (unsigned short)(u >> 16);
}
__device__ __forceinline__ float bf16_f(unsigned short h) {
    return __uint_as_float(((unsigned int)h) << 16);
}

// ============ GEMM-KQ: C[:, 0:2048] = inputs @ W[:, 0:2048] + b, stored split ============
// 128x128 tile, BK=32, 4 waves (2x2 of 64x64), split-bf16 3-term MFMA.
__global__ __launch_bounds__(256) void gemm_kq(
        const float* __restrict__ A, const float* __restrict__ Wm,
        const float* __restrict__ bias,
        unsigned short* __restrict__ khi, unsigned short* __restrict__ klo) {
    __shared__ unsigned short Ash[128*36], Asl[128*36], Bth[128*36], Btl[128*36];
    const int tid = threadIdx.x;
    const int n0 = blockIdx.x * 128;
    const int m0 = blockIdx.y * 128;
    const int lane = tid & 63, wid = tid >> 6;
    const int wm = wid >> 1, wn = wid & 1;
    const int lr = lane & 15, lc = lane >> 4;
    const int ar = tid >> 1, akc = (tid & 1) * 16;       // A staging: row, k-col base
    const int bk2 = (tid & 15) * 2, bnc = (tid >> 4) * 8; // B staging: k-row pair, n-col base

    f32x4 acc[4][4];
    #pragma unroll
    for (int i = 0; i < 4; ++i)
        #pragma unroll
        for (int j = 0; j < 4; ++j) acc[i][j] = (f32x4){0.f, 0.f, 0.f, 0.f};

    for (int k0 = 0; k0 < D_MODEL; k0 += 32) {
        const float* ap = A + (size_t)(m0 + ar) * D_MODEL + k0 + akc;
        float4 a0 = *(const float4*)(ap);
        float4 a1 = *(const float4*)(ap + 4);
        float4 a2 = *(const float4*)(ap + 8);
        float4 a3 = *(const float4*)(ap + 12);
        const float* wp0 = Wm + (size_t)(k0 + bk2) * 3072 + n0 + bnc;
        const float* wp1 = wp0 + 3072;
        float4 w00 = *(const float4*)(wp0), w01 = *(const float4*)(wp0 + 4);
        float4 w10 = *(const float4*)(wp1), w11 = *(const float4*)(wp1 + 4);
        __syncthreads();
        {
            float af[16] = {a0.x,a0.y,a0.z,a0.w, a1.x,a1.y,a1.z,a1.w,
                            a2.x,a2.y,a2.z,a2.w, a3.x,a3.y,a3.z,a3.w};
            unsigned short hs[16], ls[16];
            #pragma unroll
            for (int i = 0; i < 16; ++i) {
                hs[i] = bf16_rne(af[i]);
                ls[i] = bf16_rne(af[i] - bf16_f(hs[i]));
            }
            #pragma unroll
            for (int i = 0; i < 16; i += 4) {
                *(ushort4*)&Ash[ar*36 + akc + i] = make_ushort4(hs[i],hs[i+1],hs[i+2],hs[i+3]);
                *(ushort4*)&Asl[ar*36 + akc + i] = make_ushort4(ls[i],ls[i+1],ls[i+2],ls[i+3]);
            }
            float r0[8] = {w00.x,w00.y,w00.z,w00.w, w01.x,w01.y,w01.z,w01.w};
            float r1[8] = {w10.x,w10.y,w10.z,w10.w, w11.x,w11.y,w11.z,w11.w};
            #pragma unroll
            for (int i = 0; i < 8; ++i) {
                unsigned short h0 = bf16_rne(r0[i]), h1 = bf16_rne(r1[i]);
                unsigned short l0 = bf16_rne(r0[i] - bf16_f(h0));
                unsigned short l1 = bf16_rne(r1[i] - bf16_f(h1));
                *(ushort2*)&Bth[(bnc + i)*36 + bk2] = make_ushort2(h0, h1);
                *(ushort2*)&Btl[(bnc + i)*36 + bk2] = make_ushort2(l0, l1);
            }
        }
        __syncthreads();
        bf16x8 ah[4], al[4], bh[4], bl[4];
        #pragma unroll
        for (int i = 0; i < 4; ++i) {
            int ra = (wm*64 + i*16 + lr)*36 + lc*8;
            int rb = (wn*64 + i*16 + lr)*36 + lc*8;
            ah[i] = *(const bf16x8*)&Ash[ra];
            al[i] = *(const bf16x8*)&Asl[ra];
            bh[i] = *(const bf16x8*)&Bth[rb];
            bl[i] = *(const bf16x8*)&Btl[rb];
        }
        #pragma unroll
        for (int mi = 0; mi < 4; ++mi)
            #pragma unroll
            for (int ni = 0; ni < 4; ++ni) {
                acc[mi][ni] = __builtin_amdgcn_mfma_f32_16x16x32_bf16(ah[mi], bh[ni], acc[mi][ni], 0, 0, 0);
                acc[mi][ni] = __builtin_amdgcn_mfma_f32_16x16x32_bf16(ah[mi], bl[ni], acc[mi][ni], 0, 0, 0);
                acc[mi][ni] = __builtin_amdgcn_mfma_f32_16x16x32_bf16(al[mi], bh[ni], acc[mi][ni], 0, 0, 0);
            }
    }
    #pragma unroll
    for (int ni = 0; ni < 4; ++ni) {
        int n = n0 + wn*64 + ni*16 + lr;
        float bv = bias[n];
        #pragma unroll
        for (int mi = 0; mi < 4; ++mi)
            #pragma unroll
            for (int r = 0; r < 4; ++r) {
                int m = m0 + wm*64 + mi*16 + lc*4 + r;
                float x = acc[mi][ni][r] + bv;
                unsigned short h = bf16_rne(x);
                khi[(size_t)m*2048 + n] = h;
                klo[(size_t)m*2048 + n] = bf16_rne(x - bf16_f(h));
            }
    }
}

// ============ GEMM-V: vt[n-2048][s] = (inputs @ W[:, 2048:3072] + b)^T, stored split ============
// Same tiles; computes C^T directly by swapping MFMA operand roles (A'=W^T, B'=inputs^T).
__global__ __launch_bounds__(256) void gemm_v(
        const float* __restrict__ A, const float* __restrict__ Wm,
        const float* __restrict__ bias,
        unsigned short* __restrict__ vthi, unsigned short* __restrict__ vtlo) {
    __shared__ unsigned short Ash[128*36], Asl[128*36], Bth[128*36], Btl[128*36];
    const int tid = threadIdx.x;
    const int n0 = 2048 + blockIdx.x * 128;
    const int m0 = blockIdx.y * 128;
    const int lane = tid & 63, wid = tid >> 6;
    const int wm = wid >> 1, wn = wid & 1;
    const int lr = lane & 15, lc = lane >> 4;
    const int ar = tid >> 1, akc = (tid & 1) * 16;
    const int bk2 = (tid & 15) * 2, bnc = (tid >> 4) * 8;

    f32x4 acc[4][4];
    #pragma unroll
    for (int i = 0; i < 4; ++i)
        #pragma unroll
        for (int j = 0; j < 4; ++j) acc[i][j] = (f32x4){0.f, 0.f, 0.f, 0.f};

    for (int k0 = 0; k0 < D_MODEL; k0 += 32) {
        const float* ap = A + (size_t)(m0 + ar) * D_MODEL + k0 + akc;
        float4 a0 = *(const float4*)(ap);
        float4 a1 = *(const float4*)(ap + 4);
        float4 a2 = *(const float4*)(ap + 8);
        float4 a3 = *(const float4*)(ap + 12);
        const float* wp0 = Wm + (size_t)(k0 + bk2) * 3072 + n0 + bnc;
        const float* wp1 = wp0 + 3072;
        float4 w00 = *(const float4*)(wp0), w01 = *(const float4*)(wp0 + 4);
        float4 w10 = *(const float4*)(wp1), w11 = *(const float4*)(wp1 + 4);
        __syncthreads();
        {
            float af[16] = {a0.x,a0.y,a0.z,a0.w, a1.x,a1.y,a1.z,a1.w,
                            a2.x,a2.y,a2.z,a2.w, a3.x,a3.y,a3.z,a3.w};
            unsigned short hs[16], ls[16];
            #pragma unroll
            for (int i = 0; i < 16; ++i) {
                hs[i] = bf16_rne(af[i]);
                ls[i] = bf16_rne(af[i] - bf16_f(hs[i]));
            }
            #pragma unroll
            for (int i = 0; i < 16; i += 4) {
                *(ushort4*)&Ash[ar*36 + akc + i] = make_ushort4(hs[i],hs[i+1],hs[i+2],hs[i+3]);
                *(ushort4*)&Asl[ar*36 + akc + i] = make_ushort4(ls[i],ls[i+1],ls[i+2],ls[i+3]);
            }
            float r0[8] = {w00.x,w00.y,w00.z,w00.w, w01.x,w01.y,w01.z,w01.w};
            float r1[8] = {w10.x,w10.y,w10.z,w10.w, w11.x,w11.y,w11.z,w11.w};
            #pragma unroll
            for (int i = 0; i < 8; ++i) {
                unsigned short h0 = bf16_rne(r0[i]), h1 = bf16_rne(r1[i]);
                unsigned short l0 = bf16_rne(r0[i] - bf16_f(h0));
                unsigned short l1 = bf16_rne(r1[i] - bf16_f(h1));
                *(ushort2*)&Bth[(bnc + i)*36 + bk2] = make_ushort2(h0, h1);
                *(ushort2*)&Btl[(bnc + i)*36 + bk2] = make_ushort2(l0, l1);
            }
        }
        __syncthreads();
        bf16x8 nh[4], nl[4], sh[4], sl[4];
        #pragma unroll
        for (int i = 0; i < 4; ++i) {
            int rb = (wm*64 + i*16 + lr)*36 + lc*8;   // n-side from W^T tile
            int ra = (wn*64 + i*16 + lr)*36 + lc*8;   // s-side from inputs tile
            nh[i] = *(const bf16x8*)&Bth[rb];
            nl[i] = *(const bf16x8*)&Btl[rb];
            sh[i] = *(const bf16x8*)&Ash[ra];
            sl[i] = *(const bf16x8*)&Asl[ra];
        }
        #pragma unroll
        for (int mi = 0; mi < 4; ++mi)
            #pragma unroll
            for (int ni = 0; ni < 4; ++ni) {
                acc[mi][ni] = __builtin_amdgcn_mfma_f32_16x16x32_bf16(nh[mi], sh[ni], acc[mi][ni], 0, 0, 0);
                acc[mi][ni] = __builtin_amdgcn_mfma_f32_16x16x32_bf16(nh[mi], sl[ni], acc[mi][ni], 0, 0, 0);
                acc[mi][ni] = __builtin_amdgcn_mfma_f32_16x16x32_bf16(nl[mi], sh[ni], acc[mi][ni], 0, 0, 0);
            }
    }
    // D'[n][s]: row = n (gets bias), col = s
    #pragma unroll
    for (int mi = 0; mi < 4; ++mi)
        #pragma unroll
        for (int r = 0; r < 4; ++r) {
            int nr = n0 + wm*64 + mi*16 + lc*4 + r;     // global col index in [2048,3072)
            float bv = bias[nr];
            int vrow = nr - 2048;
            #pragma unroll
            for (int ni = 0; ni < 4; ++ni) {
                int sg = m0 + wn*64 + ni*16 + lr;
                float x = acc[mi][ni][r] + bv;
                unsigned short h = bf16_rne(x);
                vthi[(size_t)vrow*4096 + sg] = h;
                vtlo[(size_t)vrow*4096 + sg] = bf16_rne(x - bf16_f(h));
            }
        }
}

// ============ Fused attention: MFMA QK^T (3-term split) + exp(elu-clip) + MFMA PV ============
// 4 waves x 32 q-rows = 128-q block. All fragments direct from global (L2-resident).
// Only LDS: per-wave w-transpose buffer. No __syncthreads in the k-loop.
__global__ __launch_bounds__(256) void attn_mfma(
        const unsigned short* __restrict__ khi, const unsigned short* __restrict__ klo,
        const unsigned short* __restrict__ vthi, const unsigned short* __restrict__ vtlo,
        const float* __restrict__ masks, float* __restrict__ out) {
    __shared__ unsigned short Wt[4][32*72];
    const int tid = threadIdx.x;
    const int lane = tid & 63, wid = tid >> 6;
    const int lr = lane & 15, lc = lane >> 4;
    const int h = blockIdx.y, b = blockIdx.z;
    const int qw = blockIdx.x * 128 + wid * 32;      // wave's first q row
    const size_t srow = (size_t)b * S_LEN;

    // Q fragments (hi/lo), kept in registers for the whole block
    bf16x8 qh[2][2], ql[2][2];
    #pragma unroll
    for (int mi = 0; mi < 2; ++mi)
        #pragma unroll
        for (int ks = 0; ks < 2; ++ks) {
            size_t off = (srow + qw + mi*16 + lr) * 2048 + 1024 + h*64 + ks*32 + lc*8;
            qh[mi][ks] = *(const bf16x8*)(khi + off);
            ql[mi][ks] = *(const bf16x8*)(klo + off);
        }

    f32x4 acc[2][4];
    float den[2][4];
    #pragma unroll
    for (int mi = 0; mi < 2; ++mi)
        #pragma unroll
        for (int ni = 0; ni < 4; ++ni) acc[mi][ni] = (f32x4){0.f, 0.f, 0.f, 0.f};
    #pragma unroll
    for (int mi = 0; mi < 2; ++mi)
        #pragma unroll
        for (int r = 0; r < 4; ++r) den[mi][r] = 0.f;

    for (int k0 = 0; k0 < S_LEN; k0 += 64) {
        // K fragments
        bf16x8 kh[4][2], kl[4][2];
        #pragma unroll
        for (int ni = 0; ni < 4; ++ni)
            #pragma unroll
            for (int ks = 0; ks < 2; ++ks) {
                size_t off = (srow + k0 + ni*16 + lr) * 2048 + h*64 + ks*32 + lc*8;
                kh[ni][ks] = *(const bf16x8*)(khi + off);
                kl[ni][ks] = *(const bf16x8*)(klo + off);
            }
        // U = Q K^T (3-term split)
        f32x4 u[2][4];
        #pragma unroll
        for (int mi = 0; mi < 2; ++mi)
            #pragma unroll
            for (int ni = 0; ni < 4; ++ni) u[mi][ni] = (f32x4){0.f, 0.f, 0.f, 0.f};
        #pragma unroll
        for (int ks = 0; ks < 2; ++ks)
            #pragma unroll
            for (int ni = 0; ni < 4; ++ni)
                #pragma unroll
                for (int mi = 0; mi < 2; ++mi) {
                    u[mi][ni] = __builtin_amdgcn_mfma_f32_16x16x32_bf16(qh[mi][ks], kh[ni][ks], u[mi][ni], 0, 0, 0);
                    u[mi][ni] = __builtin_amdgcn_mfma_f32_16x16x32_bf16(qh[mi][ks], kl[ni][ks], u[mi][ni], 0, 0, 0);
                    u[mi][ni] = __builtin_amdgcn_mfma_f32_16x16x32_bf16(ql[mi][ks], kh[ni][ks], u[mi][ni], 0, 0, 0);
                }
        // w = exp(clip(elu(u))) * mask_k, accumulate den from bf16-rounded w
        float mk[4];
        #pragma unroll
        for (int ni = 0; ni < 4; ++ni) mk[ni] = masks[b*S_LEN + k0 + ni*16 + lr];
        #pragma unroll
        for (int mi = 0; mi < 2; ++mi)
            #pragma unroll
            for (int ni = 0; ni < 4; ++ni)
                #pragma unroll
                for (int r = 0; r < 4; ++r) {
                    float x = u[mi][ni][r];
                    float e = __expf(fminf(x, 0.f));
                    float t = x > 0.f ? x : e - 1.f;   // elu (lower clip moot: elu > -1)
                    t = fminf(t, 10.f);
                    float w = __expf(t) * mk[ni];
                    unsigned short wb = bf16_rne(w);
                    den[mi][r] += bf16_f(wb);
                    Wt[wid][(mi*16 + lc*4 + r)*72 + ni*16 + lr] = wb;
                }
        // PV: acc += w * V  (w single bf16, V split hi/lo)
        #pragma unroll
        for (int ks = 0; ks < 2; ++ks) {
            bf16x8 pa0 = *(const bf16x8*)&Wt[wid][(lr)*72 + ks*32 + lc*8];
            bf16x8 pa1 = *(const bf16x8*)&Wt[wid][(16 + lr)*72 + ks*32 + lc*8];
            #pragma unroll
            for (int ni = 0; ni < 4; ++ni) {
                size_t voff = (size_t)(h*64 + ni*16 + lr) * 4096 + srow + k0 + ks*32 + lc*8;
                bf16x8 vh = *(const bf16x8*)(vthi + voff);
                bf16x8 vl = *(const bf16x8*)(vtlo + voff);
                acc[0][ni] = __builtin_amdgcn_mfma_f32_16x16x32_bf16(pa0, vh, acc[0][ni], 0, 0, 0);
                acc[0][ni] = __builtin_amdgcn_mfma_f32_16x16x32_bf16(pa0, vl, acc[0][ni], 0, 0, 0);
                acc[1][ni] = __builtin_amdgcn_mfma_f32_16x16x32_bf16(pa1, vh, acc[1][ni], 0, 0, 0);
                acc[1][ni] = __builtin_amdgcn_mfma_f32_16x16x32_bf16(pa1, vl, acc[1][ni], 0, 0, 0);
            }
        }
    }
    // reduce den across the 16 lanes holding one q-row's 16 k-columns
    #pragma unroll
    for (int mi = 0; mi < 2; ++mi)
        #pragma unroll
        for (int r = 0; r < 4; ++r) {
            float d = den[mi][r];
            d += __shfl_xor(d, 1);
            d += __shfl_xor(d, 2);
            d += __shfl_xor(d, 4);
            d += __shfl_xor(d, 8);
            den[mi][r] = d;
        }
    // out = acc * mask_q / den
    #pragma unroll
    for (int mi = 0; mi < 2; ++mi)
        #pragma unroll
        for (int r = 0; r < 4; ++r) {
            int q = qw + mi*16 + lc*4 + r;
            float mq = masks[b*S_LEN + q];
            float scale = mq / den[mi][r];
            #pragma unroll
            for (int ni = 0; ni < 4; ++ni)
                out[(srow + q)*D_MODEL + h*64 + ni*16 + lr] = acc[mi][ni][r] * scale;
        }
}

extern "C" void kernel_launch(void* const* d_in, const int* in_sizes, int n_in,
                              void* d_out, int out_size, void* d_ws, size_t ws_size,
                              hipStream_t stream) {
    (void)in_sizes; (void)n_in; (void)out_size; (void)ws_size;
    const float* inputs = (const float*)d_in[0];
    const float* masks  = (const float*)d_in[1];
    const float* Wm     = (const float*)d_in[2];
    const float* bias   = (const float*)d_in[3];
    float* outp = (float*)d_out;

    // ws layout (exactly 50,331,648 B, same as validated R3 footprint):
    //   khi [4096][2048] ushort, klo [4096][2048] ushort  (K cols 0..1023, Q cols 1024..2047)
    //   vthi[1024][4096] ushort, vtlo[1024][4096] ushort  (V transposed: row h*64+dd, col b*2048+k)
    unsigned short* khi  = (unsigned short*)d_ws;
    unsigned short* klo  = khi + (size_t)4096*2048;
    unsigned short* vthi = klo + (size_t)4096*2048;
    unsigned short* vtlo = vthi + (size_t)1024*4096;

    gemm_kq<<<dim3(16, 32), 256, 0, stream>>>(inputs, Wm, bias, khi, klo);
    gemm_v <<<dim3(8, 32), 256, 0, stream>>>(inputs, Wm, bias, vthi, vtlo);
    attn_mfma<<<dim3(16, NHEAD, 2), 256, 0, stream>>>(khi, klo, vthi, vtlo, masks, outp);
}